// Round 6
// baseline (8316.820 us; speedup 1.0000x reference)
//
#include <hip/hip_runtime.h>
#include <math.h>
#include <stdint.h>

// LNN: BS=16384, d=32 (n=16), HID=512. All fp32 in/out.
// H = W1 D1 W1^T + M D2 M^T,  M[i][c] = sum_j W1[i][j] s1[j] W2[j][c],
// jac = W1 (s1*u), u = W2 (W3*s2), d1 = u*s1*(1-s1).
// Kernel A: per-sample aug[16][17] = [A | rhs] -> d_ws (MFMA GEMM, exact 3-way
//           fp16 bit-split, term2 Gram from register fragments via wave-local staging).
// Kernel B: per-wave fp64 Jacobi eig pinv (JAX rcond) -> qdd.

typedef _Float16 f16x8 __attribute__((ext_vector_type(8)));
typedef float f32x4 __attribute__((ext_vector_type(4)));

#define PSTR 136               // pack row stride (halfwords), 272 B (16B-aligned)
#define PLANE (33*PSTR)        // 4488 halfwords per plane
#define NSWEEP 5
#define JAX_RCOND 1.9073486e-5 // 10 * 16 * eps_f32

// kernel A LDS float offsets: [0,6732) = pack planes (26928 B); staging [4][32*33] overlays
#define OFF_S1   6732
#define OFF_H1   (OFF_S1+512)     // h1 -> d1 overlay
#define OFF_G2   (OFF_H1+512)
#define OFF_D2   (OFF_G2+512)
#define OFF_U    (OFF_D2+512)     // u -> dz1 overlay
#define OFF_X    (OFF_U+512)      // 32
#define OFF_JAC  (OFF_X+32)       // 16
#define OFF_T2   (OFF_JAC+16)     // [16][33] = 528 (term2 + term1 accumulate here)
#define OFF_JP   (OFF_T2+528)     // jac partials [16][17] = 272
#define SMEM_FLOATS (OFF_JP+272)  // 10140
#define SMEM_BYTES  (SMEM_FLOATS*4)  // 40560 B -> 4 blocks/CU

__device__ __forceinline__ void exsplit(float a, _Float16& c0, _Float16& c1, _Float16& c2) {
    const uint32_t u = __builtin_bit_cast(uint32_t, a);
    const float a0 = __builtin_bit_cast(float, u & 0xFFFF0000u);
    const float r1 = a - a0;                       // exact
    const uint32_t v = __builtin_bit_cast(uint32_t, r1);
    const float a1 = __builtin_bit_cast(float, v & 0xFFFF0000u);
    const float a2 = r1 - a1;                      // exact, <=9 sig bits
    c0 = (_Float16)a0; c1 = (_Float16)a1; c2 = (_Float16)a2;
}

__device__ __forceinline__ uint32_t pk2(_Float16 lo, _Float16 hi) {
    return ((uint32_t)__builtin_bit_cast(unsigned short, hi) << 16) |
           (uint32_t)__builtin_bit_cast(unsigned short, lo);
}

__device__ __forceinline__ f32x4 mm8(f16x8 a0, f16x8 a1, f16x8 a2,
                                     f16x8 b0, f16x8 b1, f16x8 b2, f32x4 c) {
    c = __builtin_amdgcn_mfma_f32_16x16x32_f16(a0, b0, c, 0, 0, 0);
    c = __builtin_amdgcn_mfma_f32_16x16x32_f16(a0, b1, c, 0, 0, 0);
    c = __builtin_amdgcn_mfma_f32_16x16x32_f16(a1, b0, c, 0, 0, 0);
    c = __builtin_amdgcn_mfma_f32_16x16x32_f16(a1, b1, c, 0, 0, 0);
    c = __builtin_amdgcn_mfma_f32_16x16x32_f16(a0, b2, c, 0, 0, 0);
    c = __builtin_amdgcn_mfma_f32_16x16x32_f16(a2, b0, c, 0, 0, 0);
    c = __builtin_amdgcn_mfma_f32_16x16x32_f16(a1, b2, c, 0, 0, 0);
    c = __builtin_amdgcn_mfma_f32_16x16x32_f16(a2, b1, c, 0, 0, 0);
    return c;
}

__device__ __forceinline__ void pairpq(int r, int m, int& p, int& q) {
    p = (m == 0) ? 0 : 1 + (m - 1 + r) % 15;
    q = 1 + (14 - m + r) % 15;
}

__device__ __forceinline__ void wave_fence() {
    __builtin_amdgcn_wave_barrier();
    __builtin_amdgcn_s_waitcnt(0);
    __builtin_amdgcn_wave_barrier();
}

// ---------------- precompute: W2 -> transposed exact 3-way fp16 planes ----------------
extern "C" __global__ __launch_bounds__(256)
void w2_split_kernel(const float* __restrict__ W2,
                     _Float16* __restrict__ S0, _Float16* __restrict__ S1p,
                     _Float16* __restrict__ S2)
{
    __shared__ float til[64][65];
    const int t = threadIdx.x;
    const int k0 = (blockIdx.x >> 3) * 64;
    const int c0 = (blockIdx.x & 7) * 64;
    #pragma unroll
    for (int it = 0; it < 16; ++it) {
        const int idx = t + it*256;
        const int r = idx >> 6, c = idx & 63;
        til[r][c] = W2[(k0+r)*512 + c0 + c];
    }
    __syncthreads();
    uint32_t* q0 = (uint32_t*)S0;
    uint32_t* q1 = (uint32_t*)S1p;
    uint32_t* q2 = (uint32_t*)S2;
    const int jp = t & 31, ccb = t >> 5;
    #pragma unroll
    for (int it = 0; it < 8; ++it) {
        const int cc = ccb + it*8;
        const float w0 = til[2*jp][cc], w1 = til[2*jp+1][cc];
        _Float16 x0,x1,x2, y0,y1,y2;
        exsplit(w0, x0, x1, x2);
        exsplit(w1, y0, y1, y2);
        const int word = (c0+cc)*256 + (k0 >> 1) + jp;
        q0[word] = pk2(x0, y0);
        q1[word] = pk2(x1, y1);
        q2[word] = pk2(x2, y2);
    }
}

// ---------------- kernel A: everything except the pinv solve ----------------
extern "C" __global__ __launch_bounds__(256, 4)
void lnn_kernel(const float* __restrict__ x,
                const float* __restrict__ W1, const float* __restrict__ b1,
                const float* __restrict__ W2, const float* __restrict__ b2,
                const float* __restrict__ W3,
                const _Float16* __restrict__ S0, const _Float16* __restrict__ S1p,
                const _Float16* __restrict__ S2,
                float* __restrict__ out, float* __restrict__ augg)
{
    const int b = blockIdx.x;
    const int t = threadIdx.x;
    const int lane = t & 63;
    const int w = t >> 6;
    const int m = lane & 15;
    const int quad = lane >> 4;

    extern __shared__ float sm[];
    _Float16* s_pk  = (_Float16*)sm;          // 3 pack planes
    float*    s_stg = sm;                      // T2 staging overlay [4][32*33]
    float*    s_s1  = sm + OFF_S1;
    float*    s_h1  = sm + OFF_H1;             // h1 -> d1
    float*    s_d1  = sm + OFF_H1;
    float*    s_g2  = sm + OFF_G2;
    float*    s_d2  = sm + OFF_D2;
    float*    s_u   = sm + OFF_U;              // u -> dz1
    float*    s_x   = sm + OFF_X;
    float*    s_jac = sm + OFF_JAC;
    float*    s_T2  = sm + OFF_T2;
    float*    s_jp  = sm + OFF_JP;

    // ---- P0 ----
    if (t < 32) s_x[t] = x[b*32 + t];
    if (t < 16) out[b*32 + t] = x[b*32 + 16 + t];
    for (int i = t; i < 528; i += 256) s_T2[i] = 0.f;
    __syncthreads();

    // ---- P1: z1 -> s1, h1 ----
    #pragma unroll
    for (int rep = 0; rep < 2; ++rep) {
        const int j = t + rep*256;
        float z = b1[j];
        #pragma unroll
        for (int i = 0; i < 32; ++i) z = fmaf(s_x[i], W1[i*512 + j], z);
        const float e = expf(-fabsf(z));
        const float s = (z >= 0.f) ? 1.f/(1.f+e) : e/(1.f+e);
        s_s1[j] = s;
        s_h1[j] = fmaxf(z, 0.f) + log1pf(e);
    }
    __syncthreads();

    // ---- P2: two half-passes over columns; per half: 4 K-chunks of 128 ----
    float t2acc[8];
    #pragma unroll
    for (int k = 0; k < 8; ++k) t2acc[k] = 0.f;

    for (int half = 0; half < 2; ++half) {
        f32x4 acc0[4], acc1[4], zacc[4];
        #pragma unroll
        for (int ct = 0; ct < 4; ++ct) {
            acc0[ct] = f32x4{0.f,0.f,0.f,0.f};
            acc1[ct] = f32x4{0.f,0.f,0.f,0.f};
            zacc[ct] = f32x4{0.f,0.f,0.f,0.f};
        }

        for (int ch = 0; ch < 4; ++ch) {
            // pack rows 0..31 = W1*s1, row 32 = h1; k in [ch*128, ch*128+128)
            // XOR-ish swizzle: group g of row r stored at physical group (g+2r)&15
            {
                uint32_t* q0 = (uint32_t*)s_pk;
                #pragma unroll 1
                for (int it = 0; it < 9; ++it) {
                    const int idx = t + it*256;
                    if (idx < 2112) {
                        const int r = idx >> 6, k2 = idx & 63;
                        const int k = ch*128 + k2*2;
                        float va, vb;
                        if (r < 32) {
                            const float2 wv = *(const float2*)(W1 + r*512 + k);
                            va = wv.x * s_s1[k];
                            vb = wv.y * s_s1[k+1];
                        } else {
                            va = s_h1[k];
                            vb = s_h1[k+1];
                        }
                        _Float16 p0,p1,p2, r0,r1,r2;
                        exsplit(va, p0, p1, p2);
                        exsplit(vb, r0, r1, r2);
                        const int pg = ((k2 >> 2) + 2*r) & 15;
                        const int word = r*68 + pg*4 + (k2 & 3);
                        q0[word]        = pk2(p0, r0);
                        q0[word + 2244] = pk2(p1, r1);   // PLANE/2
                        q0[word + 4488] = pk2(p2, r2);
                    }
                }
            }
            __syncthreads();

            const _Float16 hs = (m == 0) ? (_Float16)1.0f : (_Float16)0.0f;
            #pragma unroll 1
            for (int ks = 0; ks < 4; ++ks) {
                const int g = ks*4 + quad;
                const int swm = ((g + 2*m) & 15) * 8;   // rows m and 16+m share swizzle
                const _Float16* pr0 = s_pk + m*PSTR + swm;
                const _Float16* pr1 = s_pk + (16+m)*PSTR + swm;
                const _Float16* prh = s_pk + 32*PSTR + (g & 15)*8;
                const f16x8 A00 = *(const f16x8*)(pr0);
                const f16x8 A01 = *(const f16x8*)(pr0 + PLANE);
                const f16x8 A02 = *(const f16x8*)(pr0 + 2*PLANE);
                const f16x8 A10 = *(const f16x8*)(pr1);
                const f16x8 A11 = *(const f16x8*)(pr1 + PLANE);
                const f16x8 A12 = *(const f16x8*)(pr1 + 2*PLANE);
                f16x8 H0 = *(const f16x8*)(prh) * hs;
                f16x8 H1 = *(const f16x8*)(prh + PLANE) * hs;
                f16x8 H2 = *(const f16x8*)(prh + 2*PLANE) * hs;

                const int gk = ch*128 + ks*32 + quad*8;
                #pragma unroll
                for (int ct = 0; ct < 4; ++ct) {
                    const int c = w*128 + (half*4 + ct)*16 + m;
                    const f16x8 B0 = *(const f16x8*)(S0  + c*512 + gk);
                    const f16x8 B1 = *(const f16x8*)(S1p + c*512 + gk);
                    const f16x8 B2 = *(const f16x8*)(S2  + c*512 + gk);
                    acc0[ct] = mm8(A00, A01, A02, B0, B1, B2, acc0[ct]);
                    acc1[ct] = mm8(A10, A11, A12, B0, B1, B2, acc1[ct]);
                    zacc[ct] = mm8(H0,  H1,  H2,  B0, B1, B2, zacc[ct]);
                }
            }
            __syncthreads();
        }

        // z2 epilogue for this half's 64 cols (row 0 lives in lanes 0..15, reg 0)
        if (lane < 16) {
            #pragma unroll
            for (int ct = 0; ct < 4; ++ct) {
                const int c = w*128 + (half*4 + ct)*16 + lane;
                const float z = zacc[ct].x + b2[c];
                const float e = expf(-fabsf(z));
                const float sg = (z >= 0.f) ? 1.f/(1.f+e) : e/(1.f+e);
                const float w3v = W3[c];
                s_g2[c] = w3v * sg;
                s_d2[c] = w3v * sg * (1.f - sg);
            }
        }

        // term2 partial Gram from fragments (wave-local staging, 32 cols at a time)
        {
            float* stg = s_stg + w*1056;   // [32 cols][33 rows]
            #pragma unroll 1
            for (int s2 = 0; s2 < 2; ++s2) {
                wave_fence();   // prior reads done + d2 writes visible (wave-local)
                #pragma unroll
                for (int cc = 0; cc < 2; ++cc) {
                    const int ct = 2*s2 + cc;
                    const int cl = cc*16 + m;
                    #pragma unroll
                    for (int r = 0; r < 4; ++r) {
                        stg[cl*33 + quad*4 + r]      = acc0[ct][r];
                        stg[cl*33 + 16 + quad*4 + r] = acc1[ct][r];
                    }
                }
                wave_fence();
                const int cbase = w*128 + (half*4 + 2*s2)*16;
                #pragma unroll 1
                for (int cl = 0; cl < 32; ++cl) {
                    const float mi = stg[cl*33 + 16 + m];       // M[16+m][c]
                    const float dv = s_d2[cbase + cl];
                    const float tmp = mi * dv;
                    const float* row = stg + cl*33 + quad*8;    // M[quad*8+k][c]
                    #pragma unroll
                    for (int k = 0; k < 8; ++k)
                        t2acc[k] = fmaf(tmp, row[k], t2acc[k]);
                }
            }
        }
        __syncthreads();   // staging region free for next half's pack
    }

    // fold term2 partials (4 waves -> shared)
    #pragma unroll
    for (int k = 0; k < 8; ++k)
        atomicAdd(&s_T2[m*33 + quad*8 + k], t2acc[k]);

    // ---- P3b: u[j] = W2[j,:] . g2 (16-lane groups) ----
    {
        const int lg = lane & 15, gg = lane >> 4;
        float g2r[32];
        {
            const float4* g4 = (const float4*)(s_g2 + lg*32);
            #pragma unroll
            for (int q = 0; q < 8; ++q) {
                const float4 v = g4[q];
                g2r[4*q] = v.x; g2r[4*q+1] = v.y; g2r[4*q+2] = v.z; g2r[4*q+3] = v.w;
            }
        }
        #pragma unroll 2
        for (int it = 0; it < 32; ++it) {
            const int j = w*128 + it*4 + gg;
            const float4* rw = (const float4*)(W2 + j*512 + lg*32);
            float p = 0.f;
            #pragma unroll
            for (int q = 0; q < 8; ++q) {
                const float4 v = rw[q];
                p = fmaf(v.x, g2r[4*q],   p);
                p = fmaf(v.y, g2r[4*q+1], p);
                p = fmaf(v.z, g2r[4*q+2], p);
                p = fmaf(v.w, g2r[4*q+3], p);
            }
            p += __shfl_xor(p, 1);
            p += __shfl_xor(p, 2);
            p += __shfl_xor(p, 4);
            p += __shfl_xor(p, 8);
            if (lg == 0) s_u[j] = p;
        }
    }
    __syncthreads();

    // ---- P4: dz1 = s1*u (into s_u); d1 = dz1*(1-s1) (into h1 slot) ----
    #pragma unroll
    for (int rep = 0; rep < 2; ++rep) {
        const int j = t + rep*256;
        const float uj = s_u[j], s = s_s1[j];
        const float dz = uj * s;
        s_d1[j] = dz * (1.f - s);
        s_u[j]  = dz;
    }
    __syncthreads();

    // ---- P4b: jac partials ----
    {
        const int i = t & 15, sl = t >> 4;
        float p = 0.f;
        const int j0 = sl*32;
        #pragma unroll 8
        for (int jj = 0; jj < 32; ++jj) p = fmaf(W1[i*512 + j0 + jj], s_u[j0 + jj], p);
        s_jp[i*17 + sl] = p;
    }
    __syncthreads();

    // ---- P6: jac fold; term1 (all 256 threads, 2 outputs each) += s_T2 ----
    if (t < 16) {
        float p = 0.f;
        #pragma unroll
        for (int sl = 0; sl < 16; ++sl) p += s_jp[t*17 + sl];
        s_jac[t] = p;
    }
    {
        const int i0 = 16 + (t >> 4);
        const int c0 = 2*(t & 15);
        float h00 = 0.f, h01 = 0.f;
        const float4* Wi = (const float4*)(W1 + i0*512);
        const float4* Wa = (const float4*)(W1 + c0*512);
        const float4* Wb = (const float4*)(W1 + (c0+1)*512);
        const float4* d1v = (const float4*)s_d1;
        for (int q = 0; q < 128; ++q) {
            const float4 d = d1v[q];
            const float4 ai = Wi[q], ma = Wa[q], mb = Wb[q];
            float tt;
            tt = ai.x*d.x; h00 = fmaf(tt, ma.x, h00); h01 = fmaf(tt, mb.x, h01);
            tt = ai.y*d.y; h00 = fmaf(tt, ma.y, h00); h01 = fmaf(tt, mb.y, h01);
            tt = ai.z*d.z; h00 = fmaf(tt, ma.z, h00); h01 = fmaf(tt, mb.z, h01);
            tt = ai.w*d.w; h00 = fmaf(tt, ma.w, h00); h01 = fmaf(tt, mb.w, h01);
        }
        s_T2[(i0-16)*33 + c0]     += h00;
        s_T2[(i0-16)*33 + c0 + 1] += h01;
    }
    __syncthreads();

    // ---- P7: aug = [A | rhs] -> global ----
    {
        const int r = t >> 4, c = t & 15;
        augg[(size_t)b*272 + r*17 + c] = s_T2[r*33 + 16 + c];
    }
    if (t < 16) {
        float p = s_jac[t];
        #pragma unroll
        for (int c = 0; c < 16; ++c)
            p -= s_T2[t*33 + c] * s_x[16 + c];
        augg[(size_t)b*272 + t*17 + 16] = p;
    }
}

// ---------------- kernel B: per-wave fp64 Jacobi pinv solve ----------------
extern "C" __global__ __launch_bounds__(256)
void solve_kernel(const float* __restrict__ augg, float* __restrict__ out, int bs)
{
    __shared__ double wsd[4*592];   // 18944 B -> 8 blocks/CU
    const int t = threadIdx.x & 63;
    const int w = threadIdx.x >> 6;
    const int sb = blockIdx.x*4 + w;
    if (sb >= bs) return;

    double* Ad  = wsd + w*592;      // [16][17]
    double* Vd  = Ad + 272;         // [16][17]
    double* c8  = Vd + 272;
    double* sn8 = c8 + 8;
    double* il  = sn8 + 8;
    double* yv  = il + 16;
    const float* ag = augg + (size_t)sb*272;

    for (int idx = t; idx < 272; idx += 64) {
        const int r = idx / 17, c = idx - r*17;
        double a = 0.0;
        if (c < 16) a = 0.5 * ((double)ag[r*17 + c] + (double)ag[c*17 + r]);
        Ad[idx] = a;
        Vd[idx] = (c < 16 && r == c) ? 1.0 : 0.0;
    }
    wave_fence();

    for (int sweep = 0; sweep < NSWEEP; ++sweep) {
        for (int rr = 0; rr < 15; ++rr) {
            if (t < 8) {
                int p, q; pairpq(rr, t, p, q);
                const double app = Ad[p*17 + p], aqq = Ad[q*17 + q], apq = Ad[p*17 + q];
                double cc = 1.0, ss = 0.0;
                if (apq != 0.0) {
                    const double tau = (aqq - app) / (2.0 * apq);
                    const double tt = ((tau >= 0.0) ? 1.0 : -1.0) / (fabs(tau) + sqrt(1.0 + tau*tau));
                    cc = 1.0 / sqrt(1.0 + tt*tt);
                    ss = tt * cc;
                }
                c8[t] = cc; sn8[t] = ss;
            }
            wave_fence();
            #pragma unroll
            for (int k = 0; k < 2; ++k) {      // rows: A <- J^T A
                const int id = t + 64*k;
                const int mm = id >> 4, j = id & 15;
                int p, q; pairpq(rr, mm, p, q);
                const double cc = c8[mm], ss = sn8[mm];
                const double ap = Ad[p*17 + j], aq = Ad[q*17 + j];
                Ad[p*17 + j] = cc*ap - ss*aq;
                Ad[q*17 + j] = ss*ap + cc*aq;
            }
            #pragma unroll
            for (int k = 0; k < 2; ++k) {      // V <- V J
                const int id = t + 64*k;
                const int mm = id >> 4, i = id & 15;
                int p, q; pairpq(rr, mm, p, q);
                const double cc = c8[mm], ss = sn8[mm];
                const double vp = Vd[i*17 + p], vq = Vd[i*17 + q];
                Vd[i*17 + p] = cc*vp - ss*vq;
                Vd[i*17 + q] = ss*vp + cc*vq;
            }
            wave_fence();
            #pragma unroll
            for (int k = 0; k < 2; ++k) {      // cols: A <- A J
                const int id = t + 64*k;
                const int mm = id >> 4, i = id & 15;
                int p, q; pairpq(rr, mm, p, q);
                const double cc = c8[mm], ss = sn8[mm];
                const double ap = Ad[i*17 + p], aq = Ad[i*17 + q];
                Ad[i*17 + p] = cc*ap - ss*aq;
                Ad[i*17 + q] = ss*ap + cc*aq;
            }
            wave_fence();
        }
    }

    if (t == 0) {
        double mx = 0.0;
        #pragma unroll
        for (int i = 0; i < 16; ++i) mx = fmax(mx, fabs(Ad[i*17 + i]));
        const double cut = JAX_RCOND * mx;
        #pragma unroll
        for (int i = 0; i < 16; ++i) {
            const double l = Ad[i*17 + i];
            il[i] = (fabs(l) > cut) ? (1.0 / l) : 0.0;
        }
    }
    wave_fence();

    if (t < 16) {
        double a = 0.0;
        #pragma unroll
        for (int r = 0; r < 16; ++r) a += Vd[r*17 + t] * (double)ag[r*17 + 16];
        yv[t] = a;
    }
    wave_fence();

    if (t < 16) {
        double a = 0.0;
        #pragma unroll
        for (int i = 0; i < 16; ++i) a += Vd[t*17 + i] * (il[i] * yv[i]);
        out[sb*32 + 16 + t] = (float)a;
    }
}

extern "C" void kernel_launch(void* const* d_in, const int* in_sizes, int n_in,
                              void* d_out, int out_size, void* d_ws, size_t ws_size,
                              hipStream_t stream) {
    const float* x  = (const float*)d_in[0];
    const float* W1 = (const float*)d_in[1];
    const float* b1 = (const float*)d_in[2];
    const float* W2 = (const float*)d_in[3];
    const float* b2 = (const float*)d_in[4];
    const float* W3 = (const float*)d_in[5];
    float* out = (float*)d_out;
    const int bs = in_sizes[0] / 32;

    _Float16* S0 = (_Float16*)d_ws;
    _Float16* S1 = S0 + 512*512;
    _Float16* S2 = S1 + 512*512;
    float* augg = (float*)((char*)d_ws + (size_t)3*512*512*2);   // 16384*272 fp32

    w2_split_kernel<<<dim3(64), dim3(256), 0, stream>>>(W2, S0, S1, S2);

    hipFuncSetAttribute((const void*)lnn_kernel,
                        hipFuncAttributeMaxDynamicSharedMemorySize, SMEM_BYTES);
    lnn_kernel<<<dim3(bs), dim3(256), SMEM_BYTES, stream>>>(x, W1, b1, W2, b2, W3,
                                                            S0, S1, S2, out, augg);
    solve_kernel<<<dim3((bs+3)/4), dim3(256), 0, stream>>>(augg, out, bs);
}

// Round 7
// 8214.223 us; speedup vs baseline: 1.0125x; 1.0125x over previous
//
#include <hip/hip_runtime.h>
#include <math.h>
#include <stdint.h>

// LNN: BS=16384, d=32 (n=16), HID=512. All fp32 in/out.
// H = W1 D1 W1^T + M D2 M^T,  M[i][c] = sum_j W1[i][j] s1[j] W2[j][c],
// jac = W1 (s1*u), u = W2 (W3*s2), d1 = u*s1*(1-s1).
// Kernel A (512 thr, 8 waves, 2 blocks/CU, 256-reg budget -> no spills):
//   per-sample aug[16][17] = [A | rhs] -> d_ws. MFMA GEMM with EXACT 3-way
//   bit-sliced fp16 split (8+8+8 mantissa bits, natural scales, 8 passes).
// Kernel B: per-wave fp64 Jacobi eig pinv (JAX rcond) -> qdd.

typedef _Float16 f16x8 __attribute__((ext_vector_type(8)));
typedef float f32x4 __attribute__((ext_vector_type(4)));

#define PSTR 136               // pack row stride (halfwords)
#define PLANE (33*PSTR)        // 4488 halfwords per plane
#define NSWEEP 5
#define JAX_RCOND 1.9073486e-5 // 10 * 16 * eps_f32
#define WAIT_DS_ONLY 0xC07F    // lgkmcnt(0); vmcnt=63, expcnt=7 unconstrained

// LDS float offsets: [0,6732) = 3 pack planes (26928 B); staging 8x528 overlays
#define OFF_S1   6732
#define OFF_H1   (OFF_S1+512)     // h1 -> d1 overlay
#define OFF_G2   (OFF_H1+512)
#define OFF_D2   (OFF_G2+512)
#define OFF_U    (OFF_D2+512)     // u -> dz1 overlay
#define OFF_X    (OFF_U+512)      // 32
#define OFF_JAC  (OFF_X+32)       // 16
#define OFF_T2   (OFF_JAC+16)     // [16][33] term2+term1
#define OFF_JP   (OFF_T2+528)     // jac partials [16][17]
#define SMEM_FLOATS (OFF_JP+272)  // 10140
#define SMEM_BYTES  (SMEM_FLOATS*4)  // 40560 B -> 2 blocks/CU (VGPR-limited)

__device__ __forceinline__ void exsplit(float a, _Float16& c0, _Float16& c1, _Float16& c2) {
    const uint32_t u = __builtin_bit_cast(uint32_t, a);
    const float a0 = __builtin_bit_cast(float, u & 0xFFFF0000u);
    const float r1 = a - a0;                       // exact
    const uint32_t v = __builtin_bit_cast(uint32_t, r1);
    const float a1 = __builtin_bit_cast(float, v & 0xFFFF0000u);
    const float a2 = r1 - a1;                      // exact, <=9 sig bits
    c0 = (_Float16)a0; c1 = (_Float16)a1; c2 = (_Float16)a2;
}

__device__ __forceinline__ uint32_t pk2(_Float16 lo, _Float16 hi) {
    return ((uint32_t)__builtin_bit_cast(unsigned short, hi) << 16) |
           (uint32_t)__builtin_bit_cast(unsigned short, lo);
}

__device__ __forceinline__ f32x4 mm8(f16x8 a0, f16x8 a1, f16x8 a2,
                                     f16x8 b0, f16x8 b1, f16x8 b2, f32x4 c) {
    c = __builtin_amdgcn_mfma_f32_16x16x32_f16(a0, b0, c, 0, 0, 0);
    c = __builtin_amdgcn_mfma_f32_16x16x32_f16(a0, b1, c, 0, 0, 0);
    c = __builtin_amdgcn_mfma_f32_16x16x32_f16(a1, b0, c, 0, 0, 0);
    c = __builtin_amdgcn_mfma_f32_16x16x32_f16(a1, b1, c, 0, 0, 0);
    c = __builtin_amdgcn_mfma_f32_16x16x32_f16(a0, b2, c, 0, 0, 0);
    c = __builtin_amdgcn_mfma_f32_16x16x32_f16(a2, b0, c, 0, 0, 0);
    c = __builtin_amdgcn_mfma_f32_16x16x32_f16(a1, b2, c, 0, 0, 0);
    c = __builtin_amdgcn_mfma_f32_16x16x32_f16(a2, b1, c, 0, 0, 0);
    return c;
}

__device__ __forceinline__ void pairpq(int r, int m, int& p, int& q) {
    p = (m == 0) ? 0 : 1 + (m - 1 + r) % 15;
    q = 1 + (14 - m + r) % 15;
}

__device__ __forceinline__ void ds_fence() {
    __builtin_amdgcn_wave_barrier();
    __builtin_amdgcn_s_waitcnt(WAIT_DS_ONLY);
    __builtin_amdgcn_wave_barrier();
}

__device__ __forceinline__ void wave_fence() {
    __builtin_amdgcn_wave_barrier();
    __builtin_amdgcn_s_waitcnt(0);
    __builtin_amdgcn_wave_barrier();
}

// ---------------- precompute: W2 -> transposed exact 3-way fp16 planes ----------------
extern "C" __global__ __launch_bounds__(256)
void w2_split_kernel(const float* __restrict__ W2,
                     _Float16* __restrict__ S0, _Float16* __restrict__ S1p,
                     _Float16* __restrict__ S2)
{
    __shared__ float til[64][65];
    const int t = threadIdx.x;
    const int k0 = (blockIdx.x >> 3) * 64;
    const int c0 = (blockIdx.x & 7) * 64;
    #pragma unroll
    for (int it = 0; it < 16; ++it) {
        const int idx = t + it*256;
        const int r = idx >> 6, c = idx & 63;
        til[r][c] = W2[(k0+r)*512 + c0 + c];
    }
    __syncthreads();
    uint32_t* q0 = (uint32_t*)S0;
    uint32_t* q1 = (uint32_t*)S1p;
    uint32_t* q2 = (uint32_t*)S2;
    const int jp = t & 31, ccb = t >> 5;
    #pragma unroll
    for (int it = 0; it < 8; ++it) {
        const int cc = ccb + it*8;
        const float w0 = til[2*jp][cc], w1 = til[2*jp+1][cc];
        _Float16 x0,x1,x2, y0,y1,y2;
        exsplit(w0, x0, x1, x2);
        exsplit(w1, y0, y1, y2);
        const int word = (c0+cc)*256 + (k0 >> 1) + jp;
        q0[word] = pk2(x0, y0);
        q1[word] = pk2(x1, y1);
        q2[word] = pk2(x2, y2);
    }
}

// ---------------- kernel A ----------------
extern "C" __global__ __launch_bounds__(512, 2)
void lnn_kernel(const float* __restrict__ x,
                const float* __restrict__ W1, const float* __restrict__ b1,
                const float* __restrict__ b2, const float* __restrict__ W2,
                const float* __restrict__ W3,
                const _Float16* __restrict__ S0, const _Float16* __restrict__ S1p,
                const _Float16* __restrict__ S2,
                float* __restrict__ out, float* __restrict__ augg)
{
    const int b = blockIdx.x;
    const int t = threadIdx.x;       // 0..511
    const int lane = t & 63;
    const int w = t >> 6;            // 0..7
    const int m = lane & 15;
    const int quad = lane >> 4;

    extern __shared__ float sm[];
    _Float16* s_pk  = (_Float16*)sm;   // 3 pack planes
    float*    s_stg = sm;              // Gram staging overlay [8][528]
    float*    s_s1  = sm + OFF_S1;
    float*    s_h1  = sm + OFF_H1;     // h1 -> d1
    float*    s_d1  = sm + OFF_H1;
    float*    s_g2  = sm + OFF_G2;
    float*    s_d2  = sm + OFF_D2;
    float*    s_u   = sm + OFF_U;      // u -> dz1
    float*    s_x   = sm + OFF_X;
    float*    s_jac = sm + OFF_JAC;
    float*    s_T2  = sm + OFF_T2;
    float*    s_jp  = sm + OFF_JP;

    // ---- P0 ----
    if (t < 32) s_x[t] = x[b*32 + t];
    if (t < 16) out[b*32 + t] = x[b*32 + 16 + t];
    for (int i = t; i < 528; i += 512) s_T2[i] = 0.f;
    __syncthreads();

    // ---- P1: z1 -> s1, h1 (one j per thread) ----
    {
        const int j = t;
        float z = b1[j];
        #pragma unroll
        for (int i = 0; i < 32; ++i) z = fmaf(s_x[i], W1[i*512 + j], z);
        const float e = expf(-fabsf(z));
        const float s = (z >= 0.f) ? 1.f/(1.f+e) : e/(1.f+e);
        s_s1[j] = s;
        s_h1[j] = fmaxf(z, 0.f) + log1pf(e);
    }
    __syncthreads();

    // ---- P2: single col pass (wave w -> cols w*64..w*64+64), 4 K-chunks of 128 ----
    f32x4 acc0[4], acc1[4], zacc[4];
    #pragma unroll
    for (int ct = 0; ct < 4; ++ct) {
        acc0[ct] = f32x4{0.f,0.f,0.f,0.f};
        acc1[ct] = f32x4{0.f,0.f,0.f,0.f};
        zacc[ct] = f32x4{0.f,0.f,0.f,0.f};
    }

    for (int ch = 0; ch < 4; ++ch) {
        // pack rows 0..31 = W1*s1, row 32 = h1; swizzled groups of 8 halfwords
        {
            uint32_t* q0 = (uint32_t*)s_pk;
            #pragma unroll 1
            for (int it = 0; it < 5; ++it) {
                const int idx = t + it*512;
                if (idx < 2112) {
                    const int r = idx >> 6, k2 = idx & 63;
                    const int k = ch*128 + k2*2;
                    float va, vb;
                    if (r < 32) {
                        const float2 wv = *(const float2*)(W1 + r*512 + k);
                        va = wv.x * s_s1[k];
                        vb = wv.y * s_s1[k+1];
                    } else {
                        va = s_h1[k];
                        vb = s_h1[k+1];
                    }
                    _Float16 p0,p1,p2, r0,r1,r2;
                    exsplit(va, p0, p1, p2);
                    exsplit(vb, r0, r1, r2);
                    const int pg = ((k2 >> 2) + 2*r) & 15;
                    const int word = r*68 + pg*4 + (k2 & 3);
                    q0[word]        = pk2(p0, r0);
                    q0[word + 2244] = pk2(p1, r1);   // +PLANE/2
                    q0[word + 4488] = pk2(p2, r2);   // +PLANE
                }
            }
        }
        __syncthreads();

        const _Float16 hs = (m == 0) ? (_Float16)1.0f : (_Float16)0.0f;
        #pragma unroll 1
        for (int ks = 0; ks < 4; ++ks) {
            const int g = ks*4 + quad;
            const int swm = ((g + 2*m) & 15) * 8;   // rows m and 16+m share swizzle
            const _Float16* pr0 = s_pk + m*PSTR + swm;
            const _Float16* pr1 = s_pk + (16+m)*PSTR + swm;
            const _Float16* prh = s_pk + 32*PSTR + (g & 15)*8;
            const f16x8 A00 = *(const f16x8*)(pr0);
            const f16x8 A01 = *(const f16x8*)(pr0 + PLANE);
            const f16x8 A02 = *(const f16x8*)(pr0 + 2*PLANE);
            const f16x8 A10 = *(const f16x8*)(pr1);
            const f16x8 A11 = *(const f16x8*)(pr1 + PLANE);
            const f16x8 A12 = *(const f16x8*)(pr1 + 2*PLANE);
            f16x8 H0 = *(const f16x8*)(prh) * hs;
            f16x8 H1 = *(const f16x8*)(prh + PLANE) * hs;
            f16x8 H2 = *(const f16x8*)(prh + 2*PLANE) * hs;

            const int gk = ch*128 + ks*32 + quad*8;
            #pragma unroll
            for (int ct = 0; ct < 4; ++ct) {
                const int c = w*64 + ct*16 + m;
                const f16x8 B0 = *(const f16x8*)(S0  + c*512 + gk);
                const f16x8 B1 = *(const f16x8*)(S1p + c*512 + gk);
                const f16x8 B2 = *(const f16x8*)(S2  + c*512 + gk);
                acc0[ct] = mm8(A00, A01, A02, B0, B1, B2, acc0[ct]);
                acc1[ct] = mm8(A10, A11, A12, B0, B1, B2, acc1[ct]);
                zacc[ct] = mm8(H0,  H1,  H2,  B0, B1, B2, zacc[ct]);
            }
        }
        __syncthreads();
    }

    // ---- z2 epilogue (h-row = C row 0 -> quad 0 lanes, reg .x) ----
    if (lane < 16) {
        #pragma unroll
        for (int ct = 0; ct < 4; ++ct) {
            const int c = w*64 + ct*16 + lane;
            const float z = zacc[ct].x + b2[c];
            const float e = expf(-fabsf(z));
            const float sg = (z >= 0.f) ? 1.f/(1.f+e) : e/(1.f+e);
            const float w3v = W3[c];
            s_g2[c] = w3v * sg;
            s_d2[c] = w3v * sg * (1.f - sg);
        }
    }
    __syncthreads();   // all waves done with pack region before staging overlays it

    // ---- term2 Gram from fragments (wave-local 16-col staging slices) ----
    float t2acc[8];
    #pragma unroll
    for (int k = 0; k < 8; ++k) t2acc[k] = 0.f;
    {
        float* stg = s_stg + w*528;   // [16 cols][33 rows]
        #pragma unroll
        for (int s2 = 0; s2 < 4; ++s2) {
            ds_fence();   // prior slice's reads retired
            #pragma unroll
            for (int r = 0; r < 4; ++r) {
                stg[m*33 + quad*4 + r]      = acc0[s2][r];
                stg[m*33 + 16 + quad*4 + r] = acc1[s2][r];
            }
            ds_fence();
            const int cbase = w*64 + s2*16;
            #pragma unroll 1
            for (int cl = 0; cl < 16; ++cl) {
                const float mi = stg[cl*33 + 16 + m];       // M[16+m][c]
                const float dv = s_d2[cbase + cl];
                const float tmp = mi * dv;
                const float* row = stg + cl*33 + quad*8;    // M[quad*8+k][c]
                #pragma unroll
                for (int k = 0; k < 8; ++k)
                    t2acc[k] = fmaf(tmp, row[k], t2acc[k]);
            }
        }
    }
    #pragma unroll
    for (int k = 0; k < 8; ++k)
        atomicAdd(&s_T2[m*33 + quad*8 + k], t2acc[k]);

    // ---- u[j] = W2[j,:] . g2 (16-lane groups; wave w -> 64 j) ----
    {
        const int lg = lane & 15, gg = lane >> 4;
        float g2r[32];
        {
            const float4* g4 = (const float4*)(s_g2 + lg*32);
            #pragma unroll
            for (int q = 0; q < 8; ++q) {
                const float4 v = g4[q];
                g2r[4*q] = v.x; g2r[4*q+1] = v.y; g2r[4*q+2] = v.z; g2r[4*q+3] = v.w;
            }
        }
        #pragma unroll 2
        for (int it = 0; it < 16; ++it) {
            const int j = w*64 + it*4 + gg;
            const float4* rw = (const float4*)(W2 + j*512 + lg*32);
            float p = 0.f;
            #pragma unroll
            for (int q = 0; q < 8; ++q) {
                const float4 v = rw[q];
                p = fmaf(v.x, g2r[4*q],   p);
                p = fmaf(v.y, g2r[4*q+1], p);
                p = fmaf(v.z, g2r[4*q+2], p);
                p = fmaf(v.w, g2r[4*q+3], p);
            }
            p += __shfl_xor(p, 1);
            p += __shfl_xor(p, 2);
            p += __shfl_xor(p, 4);
            p += __shfl_xor(p, 8);
            if (lg == 0) s_u[j] = p;
        }
    }
    __syncthreads();

    // ---- dz1 = s1*u (into s_u); d1 = dz1*(1-s1) (into h1 slot) ----
    {
        const int j = t;
        const float uj = s_u[j], s = s_s1[j];
        const float dz = uj * s;
        s_d1[j] = dz * (1.f - s);
        s_u[j]  = dz;
    }
    __syncthreads();

    // ---- concurrent: term1 (t<256) || jac partials (t>=256) ----
    if (t < 256) {
        const int i0 = 16 + (t >> 4);
        const int c0 = 2*(t & 15);
        float h00 = 0.f, h01 = 0.f;
        const float4* Wi = (const float4*)(W1 + i0*512);
        const float4* Wa = (const float4*)(W1 + c0*512);
        const float4* Wb = (const float4*)(W1 + (c0+1)*512);
        const float4* d1v = (const float4*)s_d1;
        for (int q = 0; q < 128; ++q) {
            const float4 d = d1v[q];
            const float4 ai = Wi[q], ma = Wa[q], mb = Wb[q];
            float tt;
            tt = ai.x*d.x; h00 = fmaf(tt, ma.x, h00); h01 = fmaf(tt, mb.x, h01);
            tt = ai.y*d.y; h00 = fmaf(tt, ma.y, h00); h01 = fmaf(tt, mb.y, h01);
            tt = ai.z*d.z; h00 = fmaf(tt, ma.z, h00); h01 = fmaf(tt, mb.z, h01);
            tt = ai.w*d.w; h00 = fmaf(tt, ma.w, h00); h01 = fmaf(tt, mb.w, h01);
        }
        s_T2[(i0-16)*33 + c0]     += h00;
        s_T2[(i0-16)*33 + c0 + 1] += h01;
    } else {
        const int tu = t & 255;
        const int i = tu & 15, sl = tu >> 4;
        float p = 0.f;
        const int j0 = sl*32;
        #pragma unroll 8
        for (int jj = 0; jj < 32; ++jj) p = fmaf(W1[i*512 + j0 + jj], s_u[j0 + jj], p);
        s_jp[i*17 + sl] = p;
    }
    __syncthreads();

    // ---- jac fold; aug = [A | rhs] -> global ----
    if (t < 16) {
        float p = 0.f;
        #pragma unroll
        for (int sl = 0; sl < 16; ++sl) p += s_jp[t*17 + sl];
        s_jac[t] = p;
    }
    __syncthreads();
    if (t < 256) {
        const int r = t >> 4, c = t & 15;
        augg[(size_t)b*272 + r*17 + c] = s_T2[r*33 + 16 + c];
    }
    if (t < 16) {
        float p = s_jac[t];
        #pragma unroll
        for (int c = 0; c < 16; ++c)
            p -= s_T2[t*33 + c] * s_x[16 + c];
        augg[(size_t)b*272 + t*17 + 16] = p;
    }
}

// ---------------- kernel B: per-wave fp64 Jacobi pinv solve ----------------
extern "C" __global__ __launch_bounds__(256)
void solve_kernel(const float* __restrict__ augg, float* __restrict__ out, int bs)
{
    __shared__ double wsd[4*592];
    const int t = threadIdx.x & 63;
    const int w = threadIdx.x >> 6;
    const int sb = blockIdx.x*4 + w;
    if (sb >= bs) return;

    double* Ad  = wsd + w*592;      // [16][17]
    double* Vd  = Ad + 272;         // [16][17]
    double* c8  = Vd + 272;
    double* sn8 = c8 + 8;
    double* il  = sn8 + 8;
    double* yv  = il + 16;
    const float* ag = augg + (size_t)sb*272;

    for (int idx = t; idx < 272; idx += 64) {
        const int r = idx / 17, c = idx - r*17;
        double a = 0.0;
        if (c < 16) a = 0.5 * ((double)ag[r*17 + c] + (double)ag[c*17 + r]);
        Ad[idx] = a;
        Vd[idx] = (c < 16 && r == c) ? 1.0 : 0.0;
    }
    wave_fence();

    for (int sweep = 0; sweep < NSWEEP; ++sweep) {
        for (int rr = 0; rr < 15; ++rr) {
            if (t < 8) {
                int p, q; pairpq(rr, t, p, q);
                const double app = Ad[p*17 + p], aqq = Ad[q*17 + q], apq = Ad[p*17 + q];
                double cc = 1.0, ss = 0.0;
                if (apq != 0.0) {
                    const double tau = (aqq - app) / (2.0 * apq);
                    const double tt = ((tau >= 0.0) ? 1.0 : -1.0) / (fabs(tau) + sqrt(1.0 + tau*tau));
                    cc = 1.0 / sqrt(1.0 + tt*tt);
                    ss = tt * cc;
                }
                c8[t] = cc; sn8[t] = ss;
            }
            wave_fence();
            #pragma unroll
            for (int k = 0; k < 2; ++k) {      // rows: A <- J^T A
                const int id = t + 64*k;
                const int mm = id >> 4, j = id & 15;
                int p, q; pairpq(rr, mm, p, q);
                const double cc = c8[mm], ss = sn8[mm];
                const double ap = Ad[p*17 + j], aq = Ad[q*17 + j];
                Ad[p*17 + j] = cc*ap - ss*aq;
                Ad[q*17 + j] = ss*ap + cc*aq;
            }
            #pragma unroll
            for (int k = 0; k < 2; ++k) {      // V <- V J
                const int id = t + 64*k;
                const int mm = id >> 4, i = id & 15;
                int p, q; pairpq(rr, mm, p, q);
                const double cc = c8[mm], ss = sn8[mm];
                const double vp = Vd[i*17 + p], vq = Vd[i*17 + q];
                Vd[i*17 + p] = cc*vp - ss*vq;
                Vd[i*17 + q] = ss*vp + cc*vq;
            }
            wave_fence();
            #pragma unroll
            for (int k = 0; k < 2; ++k) {      // cols: A <- A J
                const int id = t + 64*k;
                const int mm = id >> 4, i = id & 15;
                int p, q; pairpq(rr, mm, p, q);
                const double cc = c8[mm], ss = sn8[mm];
                const double ap = Ad[i*17 + p], aq = Ad[i*17 + q];
                Ad[i*17 + p] = cc*ap - ss*aq;
                Ad[i*17 + q] = ss*ap + cc*aq;
            }
            wave_fence();
        }
    }

    if (t == 0) {
        double mx = 0.0;
        #pragma unroll
        for (int i = 0; i < 16; ++i) mx = fmax(mx, fabs(Ad[i*17 + i]));
        const double cut = JAX_RCOND * mx;
        #pragma unroll
        for (int i = 0; i < 16; ++i) {
            const double l = Ad[i*17 + i];
            il[i] = (fabs(l) > cut) ? (1.0 / l) : 0.0;
        }
    }
    wave_fence();

    if (t < 16) {
        double a = 0.0;
        #pragma unroll
        for (int r = 0; r < 16; ++r) a += Vd[r*17 + t] * (double)ag[r*17 + 16];
        yv[t] = a;
    }
    wave_fence();

    if (t < 16) {
        double a = 0.0;
        #pragma unroll
        for (int i = 0; i < 16; ++i) a += Vd[t*17 + i] * (il[i] * yv[i]);
        out[sb*32 + 16 + t] = (float)a;
    }
}

extern "C" void kernel_launch(void* const* d_in, const int* in_sizes, int n_in,
                              void* d_out, int out_size, void* d_ws, size_t ws_size,
                              hipStream_t stream) {
    const float* x  = (const float*)d_in[0];
    const float* W1 = (const float*)d_in[1];
    const float* b1 = (const float*)d_in[2];
    const float* W2 = (const float*)d_in[3];
    const float* b2 = (const float*)d_in[4];
    const float* W3 = (const float*)d_in[5];
    float* out = (float*)d_out;
    const int bs = in_sizes[0] / 32;

    _Float16* S0 = (_Float16*)d_ws;
    _Float16* S1 = S0 + 512*512;
    _Float16* S2 = S1 + 512*512;
    float* augg = (float*)((char*)d_ws + (size_t)3*512*512*2);   // 16384*272 fp32

    w2_split_kernel<<<dim3(64), dim3(256), 0, stream>>>(W2, S0, S1, S2);

    hipFuncSetAttribute((const void*)lnn_kernel,
                        hipFuncAttributeMaxDynamicSharedMemorySize, SMEM_BYTES);
    lnn_kernel<<<dim3(bs), dim3(512), SMEM_BYTES, stream>>>(x, W1, b1, b2, W2, W3,
                                                            S0, S1, S2, out, augg);
    solve_kernel<<<dim3((bs+3)/4), dim3(256), 0, stream>>>(augg, out, bs);
}

// Round 8
// 7843.863 us; speedup vs baseline: 1.0603x; 1.0472x over previous
//
#include <hip/hip_runtime.h>
#include <math.h>
#include <stdint.h>

// LNN: BS=16384, d=32 (n=16), HID=512. All fp32 in/out.
// H = W1 D1 W1^T + M D2 M^T,  M[i][c] = sum_j W1[i][j] s1[j] W2[j][c],
// jac = W1 (s1*u), u = W2 (W3*s2), d1 = u*s1*(1-s1).
// Kernel A (512 thr): aug[16][17] = [A | rhs] -> d_ws.
//   GEMM M via EXACT 3-way bit-sliced fp16 split (8 MFMA passes, fp32-accurate);
//   z2 on VALU (coalesced W2 stream) -> A-tile is exactly 2x16 rows.
// Kernel B: per-wave fp64 Jacobi eig pinv (JAX rcond) -> qdd.

typedef _Float16 f16x8 __attribute__((ext_vector_type(8)));
typedef float f32x4 __attribute__((ext_vector_type(4)));

#define PSTR2 264              // pack row stride (halfwords) for K=256 chunk
#define PLANE2 8448            // 32*264 halfwords per plane
#define NSWEEP 5
#define JAX_RCOND 1.9073486e-5 // 10 * 16 * eps_f32
#define WAIT_DS_ONLY 0xC07F    // lgkmcnt(0); vmcnt/expcnt unconstrained

// LDS float offsets: [0,12672) = 3 pack planes (50688 B); Gram staging overlays
#define OFF_S1   12672
#define OFF_H1   (OFF_S1+512)     // h1 -> d1 overlay
#define OFF_G2   (OFF_H1+512)
#define OFF_D2   (OFF_G2+512)
#define OFF_U    (OFF_D2+512)     // u -> dz1 overlay
#define OFF_X    (OFF_U+512)      // 32
#define OFF_JAC  (OFF_X+32)       // 16
#define OFF_T2   (OFF_JAC+16)     // [16][33] term1+term2
#define OFF_JP   (OFF_T2+528)     // jac partials [16][17]
#define SMEM_FLOATS (OFF_JP+272)  // 16080
#define SMEM_BYTES  (SMEM_FLOATS*4)  // 64320 B -> 2 blocks/CU

__device__ __forceinline__ void exsplit(float a, _Float16& c0, _Float16& c1, _Float16& c2) {
    const uint32_t u = __builtin_bit_cast(uint32_t, a);
    const float a0 = __builtin_bit_cast(float, u & 0xFFFF0000u);
    const float r1 = a - a0;                       // exact
    const uint32_t v = __builtin_bit_cast(uint32_t, r1);
    const float a1 = __builtin_bit_cast(float, v & 0xFFFF0000u);
    const float a2 = r1 - a1;                      // exact, <=9 sig bits
    c0 = (_Float16)a0; c1 = (_Float16)a1; c2 = (_Float16)a2;
}

__device__ __forceinline__ uint32_t pk2(_Float16 lo, _Float16 hi) {
    return ((uint32_t)__builtin_bit_cast(unsigned short, hi) << 16) |
           (uint32_t)__builtin_bit_cast(unsigned short, lo);
}

__device__ __forceinline__ f32x4 mm8(f16x8 a0, f16x8 a1, f16x8 a2,
                                     f16x8 b0, f16x8 b1, f16x8 b2, f32x4 c) {
    c = __builtin_amdgcn_mfma_f32_16x16x32_f16(a0, b0, c, 0, 0, 0);
    c = __builtin_amdgcn_mfma_f32_16x16x32_f16(a0, b1, c, 0, 0, 0);
    c = __builtin_amdgcn_mfma_f32_16x16x32_f16(a1, b0, c, 0, 0, 0);
    c = __builtin_amdgcn_mfma_f32_16x16x32_f16(a1, b1, c, 0, 0, 0);
    c = __builtin_amdgcn_mfma_f32_16x16x32_f16(a0, b2, c, 0, 0, 0);
    c = __builtin_amdgcn_mfma_f32_16x16x32_f16(a2, b0, c, 0, 0, 0);
    c = __builtin_amdgcn_mfma_f32_16x16x32_f16(a1, b2, c, 0, 0, 0);
    c = __builtin_amdgcn_mfma_f32_16x16x32_f16(a2, b1, c, 0, 0, 0);
    return c;
}

__device__ __forceinline__ void pairpq(int r, int m, int& p, int& q) {
    p = (m == 0) ? 0 : 1 + (m - 1 + r) % 15;
    q = 1 + (14 - m + r) % 15;
}

__device__ __forceinline__ void ds_fence() {
    __builtin_amdgcn_wave_barrier();
    __builtin_amdgcn_s_waitcnt(WAIT_DS_ONLY);
    __builtin_amdgcn_wave_barrier();
}

__device__ __forceinline__ void wave_fence() {
    __builtin_amdgcn_wave_barrier();
    __builtin_amdgcn_s_waitcnt(0);
    __builtin_amdgcn_wave_barrier();
}

// ---------------- precompute: W2 -> transposed exact 3-way fp16 planes ----------------
extern "C" __global__ __launch_bounds__(256)
void w2_split_kernel(const float* __restrict__ W2,
                     _Float16* __restrict__ S0, _Float16* __restrict__ S1p,
                     _Float16* __restrict__ S2)
{
    __shared__ float til[64][65];
    const int t = threadIdx.x;
    const int k0 = (blockIdx.x >> 3) * 64;
    const int c0 = (blockIdx.x & 7) * 64;
    #pragma unroll
    for (int it = 0; it < 16; ++it) {
        const int idx = t + it*256;
        const int r = idx >> 6, c = idx & 63;
        til[r][c] = W2[(k0+r)*512 + c0 + c];
    }
    __syncthreads();
    uint32_t* q0 = (uint32_t*)S0;
    uint32_t* q1 = (uint32_t*)S1p;
    uint32_t* q2 = (uint32_t*)S2;
    const int jp = t & 31, ccb = t >> 5;
    #pragma unroll
    for (int it = 0; it < 8; ++it) {
        const int cc = ccb + it*8;
        const float w0 = til[2*jp][cc], w1 = til[2*jp+1][cc];
        _Float16 x0,x1,x2, y0,y1,y2;
        exsplit(w0, x0, x1, x2);
        exsplit(w1, y0, y1, y2);
        const int word = (c0+cc)*256 + (k0 >> 1) + jp;
        q0[word] = pk2(x0, y0);
        q1[word] = pk2(x1, y1);
        q2[word] = pk2(x2, y2);
    }
}

// ---------------- kernel A ----------------
extern "C" __global__ __launch_bounds__(512, 4)
void lnn_kernel(const float* __restrict__ x,
                const float* __restrict__ W1, const float* __restrict__ b1,
                const float* __restrict__ W2, const float* __restrict__ b2,
                const float* __restrict__ W3,
                const _Float16* __restrict__ S0, const _Float16* __restrict__ S1p,
                const _Float16* __restrict__ S2,
                float* __restrict__ out, float* __restrict__ augg)
{
    const int b = blockIdx.x;
    const int t = threadIdx.x;       // 0..511
    const int lane = t & 63;
    const int w = t >> 6;            // 0..7
    const int m = lane & 15;
    const int quad = lane >> 4;

    extern __shared__ float sm[];
    _Float16* s_pk  = (_Float16*)sm;   // 3 pack planes [32][PSTR2]
    float*    s_stg = sm;              // Gram staging overlay [8][528]
    float*    s_s1  = sm + OFF_S1;
    float*    s_h1  = sm + OFF_H1;     // h1 -> d1
    float*    s_d1  = sm + OFF_H1;
    float*    s_g2  = sm + OFF_G2;
    float*    s_d2  = sm + OFF_D2;
    float*    s_u   = sm + OFF_U;      // u -> dz1
    float*    s_x   = sm + OFF_X;
    float*    s_jac = sm + OFF_JAC;
    float*    s_T2  = sm + OFF_T2;
    float*    s_jp  = sm + OFF_JP;

    // ---- P0 ----
    if (t < 32) s_x[t] = x[b*32 + t];
    if (t < 16) out[b*32 + t] = x[b*32 + 16 + t];
    for (int i = t; i < 528; i += 512) s_T2[i] = 0.f;
    __syncthreads();

    // ---- P1: z1 -> s1, h1 (thread t -> col t) ----
    {
        const int j = t;
        float z = b1[j];
        #pragma unroll
        for (int i = 0; i < 32; ++i) z = fmaf(s_x[i], W1[i*512 + j], z);
        const float e = expf(-fabsf(z));
        const float s = (z >= 0.f) ? 1.f/(1.f+e) : e/(1.f+e);
        s_s1[j] = s;
        s_h1[j] = fmaxf(z, 0.f) + log1pf(e);
    }
    __syncthreads();

    // ---- P1.5: z2 on VALU (thread t -> col t; coalesced W2 column stream) ----
    {
        const int c = t;
        float z = b2[c];
        #pragma unroll 8
        for (int j = 0; j < 512; ++j)
            z = fmaf(s_h1[j], W2[j*512 + c], z);
        const float e = expf(-fabsf(z));
        const float sg = (z >= 0.f) ? 1.f/(1.f+e) : e/(1.f+e);
        const float w3v = W3[c];
        s_g2[c] = w3v * sg;
        s_d2[c] = w3v * sg * (1.f - sg);
    }
    __syncthreads();

    // ---- P2: u[j] = W2[j,:] . g2 (16-lane groups; wave w -> j in w*64..) ----
    {
        const int lg = lane & 15, gg = lane >> 4;
        float g2r[32];
        {
            const float4* g4 = (const float4*)(s_g2 + lg*32);
            #pragma unroll
            for (int q = 0; q < 8; ++q) {
                const float4 v = g4[q];
                g2r[4*q] = v.x; g2r[4*q+1] = v.y; g2r[4*q+2] = v.z; g2r[4*q+3] = v.w;
            }
        }
        #pragma unroll 2
        for (int it = 0; it < 16; ++it) {
            const int j = w*64 + it*4 + gg;
            const float4* rw = (const float4*)(W2 + j*512 + lg*32);
            float p = 0.f;
            #pragma unroll
            for (int q = 0; q < 8; ++q) {
                const float4 v = rw[q];
                p = fmaf(v.x, g2r[4*q],   p);
                p = fmaf(v.y, g2r[4*q+1], p);
                p = fmaf(v.z, g2r[4*q+2], p);
                p = fmaf(v.w, g2r[4*q+3], p);
            }
            p += __shfl_xor(p, 1);
            p += __shfl_xor(p, 2);
            p += __shfl_xor(p, 4);
            p += __shfl_xor(p, 8);
            if (lg == 0) s_u[j] = p;
        }
    }
    __syncthreads();

    // ---- P3: dz1 = s1*u (into s_u); d1 = dz1*(1-s1) (into h1 slot) ----
    {
        const int j = t;
        const float uj = s_u[j], s = s_s1[j];
        const float dz = uj * s;
        s_d1[j] = dz * (1.f - s);
        s_u[j]  = dz;
    }
    __syncthreads();

    // ---- P4: term1 (t<256) || jac partials (t>=256) ----
    if (t < 256) {
        const int i0 = 16 + (t >> 4);
        const int c0 = 2*(t & 15);
        float h00 = 0.f, h01 = 0.f;
        const float4* Wi = (const float4*)(W1 + i0*512);
        const float4* Wa = (const float4*)(W1 + c0*512);
        const float4* Wb = (const float4*)(W1 + (c0+1)*512);
        const float4* d1v = (const float4*)s_d1;
        for (int q = 0; q < 128; ++q) {
            const float4 d = d1v[q];
            const float4 ai = Wi[q], ma = Wa[q], mb = Wb[q];
            float tt;
            tt = ai.x*d.x; h00 = fmaf(tt, ma.x, h00); h01 = fmaf(tt, mb.x, h01);
            tt = ai.y*d.y; h00 = fmaf(tt, ma.y, h00); h01 = fmaf(tt, mb.y, h01);
            tt = ai.z*d.z; h00 = fmaf(tt, ma.z, h00); h01 = fmaf(tt, mb.z, h01);
            tt = ai.w*d.w; h00 = fmaf(tt, ma.w, h00); h01 = fmaf(tt, mb.w, h01);
        }
        s_T2[(i0-16)*33 + c0]     += h00;
        s_T2[(i0-16)*33 + c0 + 1] += h01;
    } else {
        const int tu = t & 255;
        const int i = tu & 15, sl = tu >> 4;
        float p = 0.f;
        const int j0 = sl*32;
        #pragma unroll 8
        for (int jj = 0; jj < 32; ++jj) p = fmaf(W1[i*512 + j0 + jj], s_u[j0 + jj], p);
        s_jp[i*17 + sl] = p;
    }
    __syncthreads();

    // jac fold (covered by chunk loop's first barrier)
    if (t < 16) {
        float p = 0.f;
        #pragma unroll
        for (int sl = 0; sl < 16; ++sl) p += s_jp[t*17 + sl];
        s_jac[t] = p;
    }

    // ---- P5: GEMM M = ws1 @ W2split: 2 K-chunks of 256, wave w -> cols w*64.. ----
    f32x4 acc0[4], acc1[4];
    #pragma unroll
    for (int ct = 0; ct < 4; ++ct) {
        acc0[ct] = f32x4{0.f,0.f,0.f,0.f};
        acc1[ct] = f32x4{0.f,0.f,0.f,0.f};
    }

    for (int ch = 0; ch < 2; ++ch) {
        // pack rows 0..31 = W1*s1, k in [ch*256, ch*256+256); swizzled 16B groups
        {
            uint32_t* q0 = (uint32_t*)s_pk;
            #pragma unroll
            for (int it = 0; it < 8; ++it) {
                const int idx = t + it*512;          // 0..4095
                const int r = idx >> 7, k2 = idx & 127;
                const int k = ch*256 + k2*2;
                const float2 wv = *(const float2*)(W1 + r*512 + k);
                const float va = wv.x * s_s1[k];
                const float vb = wv.y * s_s1[k+1];
                _Float16 p0,p1,p2, r0,r1,r2;
                exsplit(va, p0, p1, p2);
                exsplit(vb, r0, r1, r2);
                const int pg = ((k2 >> 2) + 2*r) & 31;
                const int word = r*132 + pg*4 + (k2 & 3);
                q0[word]        = pk2(p0, r0);
                q0[word + 4224] = pk2(p1, r1);   // +PLANE2/2
                q0[word + 8448] = pk2(p2, r2);   // +PLANE2
            }
        }
        __syncthreads();

        #pragma unroll 2
        for (int ks = 0; ks < 8; ++ks) {
            const int g = ks*4 + quad;
            const int sw = ((g + 2*m) & 31) * 8;
            const _Float16* pr0 = s_pk + m*PSTR2 + sw;
            const _Float16* pr1 = s_pk + (16+m)*PSTR2 + sw;
            const f16x8 A00 = *(const f16x8*)(pr0);
            const f16x8 A01 = *(const f16x8*)(pr0 + PLANE2);
            const f16x8 A02 = *(const f16x8*)(pr0 + 2*PLANE2);
            const f16x8 A10 = *(const f16x8*)(pr1);
            const f16x8 A11 = *(const f16x8*)(pr1 + PLANE2);
            const f16x8 A12 = *(const f16x8*)(pr1 + 2*PLANE2);

            const int gk = ch*256 + ks*32 + quad*8;
            #pragma unroll
            for (int ct = 0; ct < 4; ++ct) {
                const int c = w*64 + ct*16 + m;
                const f16x8 B0 = *(const f16x8*)(S0  + c*512 + gk);
                const f16x8 B1 = *(const f16x8*)(S1p + c*512 + gk);
                const f16x8 B2 = *(const f16x8*)(S2  + c*512 + gk);
                acc0[ct] = mm8(A00, A01, A02, B0, B1, B2, acc0[ct]);
                acc1[ct] = mm8(A10, A11, A12, B0, B1, B2, acc1[ct]);
            }
        }
        __syncthreads();
    }

    // ---- P6: term2 Gram from fragments (wave-local 16-col staging slices) ----
    float t2acc[8];
    #pragma unroll
    for (int k = 0; k < 8; ++k) t2acc[k] = 0.f;
    {
        float* stg = s_stg + w*528;   // [16 cols][33 rows]
        #pragma unroll
        for (int s2 = 0; s2 < 4; ++s2) {
            ds_fence();
            #pragma unroll
            for (int r = 0; r < 4; ++r) {
                stg[m*33 + quad*4 + r]      = acc0[s2][r];
                stg[m*33 + 16 + quad*4 + r] = acc1[s2][r];
            }
            ds_fence();
            const int cbase = w*64 + s2*16;
            #pragma unroll 1
            for (int cl = 0; cl < 16; ++cl) {
                const float mi = stg[cl*33 + 16 + m];       // M[16+m][c]
                const float dv = s_d2[cbase + cl];
                const float tmp = mi * dv;
                const float* row = stg + cl*33 + quad*8;    // M[quad*8+k][c]
                #pragma unroll
                for (int k = 0; k < 8; ++k)
                    t2acc[k] = fmaf(tmp, row[k], t2acc[k]);
            }
        }
    }
    #pragma unroll
    for (int k = 0; k < 8; ++k)
        atomicAdd(&s_T2[m*33 + quad*8 + k], t2acc[k]);
    __syncthreads();

    // ---- P7: aug = [A | rhs] -> global ----
    if (t < 256) {
        const int r = t >> 4, c = t & 15;
        augg[(size_t)b*272 + r*17 + c] = s_T2[r*33 + 16 + c];
    }
    if (t < 16) {
        float p = s_jac[t];
        #pragma unroll
        for (int c = 0; c < 16; ++c)
            p -= s_T2[t*33 + c] * s_x[16 + c];
        augg[(size_t)b*272 + t*17 + 16] = p;
    }
}

// ---------------- kernel B: per-wave fp64 Jacobi pinv solve ----------------
extern "C" __global__ __launch_bounds__(256)
void solve_kernel(const float* __restrict__ augg, float* __restrict__ out, int bs)
{
    __shared__ double wsd[4*592];
    const int t = threadIdx.x & 63;
    const int w = threadIdx.x >> 6;
    const int sb = blockIdx.x*4 + w;
    if (sb >= bs) return;

    double* Ad  = wsd + w*592;      // [16][17]
    double* Vd  = Ad + 272;         // [16][17]
    double* c8  = Vd + 272;
    double* sn8 = c8 + 8;
    double* il  = sn8 + 8;
    double* yv  = il + 16;
    const float* ag = augg + (size_t)sb*272;

    for (int idx = t; idx < 272; idx += 64) {
        const int r = idx / 17, c = idx - r*17;
        double a = 0.0;
        if (c < 16) a = 0.5 * ((double)ag[r*17 + c] + (double)ag[c*17 + r]);
        Ad[idx] = a;
        Vd[idx] = (c < 16 && r == c) ? 1.0 : 0.0;
    }
    wave_fence();

    for (int sweep = 0; sweep < NSWEEP; ++sweep) {
        for (int rr = 0; rr < 15; ++rr) {
            if (t < 8) {
                int p, q; pairpq(rr, t, p, q);
                const double app = Ad[p*17 + p], aqq = Ad[q*17 + q], apq = Ad[p*17 + q];
                double cc = 1.0, ss = 0.0;
                if (apq != 0.0) {
                    const double tau = (aqq - app) / (2.0 * apq);
                    const double tt = ((tau >= 0.0) ? 1.0 : -1.0) / (fabs(tau) + sqrt(1.0 + tau*tau));
                    cc = 1.0 / sqrt(1.0 + tt*tt);
                    ss = tt * cc;
                }
                c8[t] = cc; sn8[t] = ss;
            }
            wave_fence();
            #pragma unroll
            for (int k = 0; k < 2; ++k) {      // rows: A <- J^T A
                const int id = t + 64*k;
                const int mm = id >> 4, j = id & 15;
                int p, q; pairpq(rr, mm, p, q);
                const double cc = c8[mm], ss = sn8[mm];
                const double ap = Ad[p*17 + j], aq = Ad[q*17 + j];
                Ad[p*17 + j] = cc*ap - ss*aq;
                Ad[q*17 + j] = ss*ap + cc*aq;
            }
            #pragma unroll
            for (int k = 0; k < 2; ++k) {      // V <- V J
                const int id = t + 64*k;
                const int mm = id >> 4, i = id & 15;
                int p, q; pairpq(rr, mm, p, q);
                const double cc = c8[mm], ss = sn8[mm];
                const double vp = Vd[i*17 + p], vq = Vd[i*17 + q];
                Vd[i*17 + p] = cc*vp - ss*vq;
                Vd[i*17 + q] = ss*vp + cc*vq;
            }
            wave_fence();
            #pragma unroll
            for (int k = 0; k < 2; ++k) {      // cols: A <- A J
                const int id = t + 64*k;
                const int mm = id >> 4, i = id & 15;
                int p, q; pairpq(rr, mm, p, q);
                const double cc = c8[mm], ss = sn8[mm];
                const double ap = Ad[i*17 + p], aq = Ad[i*17 + q];
                Ad[i*17 + p] = cc*ap - ss*aq;
                Ad[i*17 + q] = ss*ap + cc*aq;
            }
            wave_fence();
        }
    }

    if (t == 0) {
        double mx = 0.0;
        #pragma unroll
        for (int i = 0; i < 16; ++i) mx = fmax(mx, fabs(Ad[i*17 + i]));
        const double cut = JAX_RCOND * mx;
        #pragma unroll
        for (int i = 0; i < 16; ++i) {
            const double l = Ad[i*17 + i];
            il[i] = (fabs(l) > cut) ? (1.0 / l) : 0.0;
        }
    }
    wave_fence();

    if (t < 16) {
        double a = 0.0;
        #pragma unroll
        for (int r = 0; r < 16; ++r) a += Vd[r*17 + t] * (double)ag[r*17 + 16];
        yv[t] = a;
    }
    wave_fence();

    if (t < 16) {
        double a = 0.0;
        #pragma unroll
        for (int i = 0; i < 16; ++i) a += Vd[t*17 + i] * (il[i] * yv[i]);
        out[sb*32 + 16 + t] = (float)a;
    }
}

extern "C" void kernel_launch(void* const* d_in, const int* in_sizes, int n_in,
                              void* d_out, int out_size, void* d_ws, size_t ws_size,
                              hipStream_t stream) {
    const float* x  = (const float*)d_in[0];
    const float* W1 = (const float*)d_in[1];
    const float* b1 = (const float*)d_in[2];
    const float* W2 = (const float*)d_in[3];
    const float* b2 = (const float*)d_in[4];
    const float* W3 = (const float*)d_in[5];
    float* out = (float*)d_out;
    const int bs = in_sizes[0] / 32;

    _Float16* S0 = (_Float16*)d_ws;
    _Float16* S1 = S0 + 512*512;
    _Float16* S2 = S1 + 512*512;
    float* augg = (float*)((char*)d_ws + (size_t)3*512*512*2);   // 16384*272 fp32

    w2_split_kernel<<<dim3(64), dim3(256), 0, stream>>>(W2, S0, S1, S2);

    hipFuncSetAttribute((const void*)lnn_kernel,
                        hipFuncAttributeMaxDynamicSharedMemorySize, SMEM_BYTES);
    lnn_kernel<<<dim3(bs), dim3(512), SMEM_BYTES, stream>>>(x, W1, b1, W2, b2, W3,
                                                            S0, S1, S2, out, augg);
    solve_kernel<<<dim3((bs+3)/4), dim3(256), 0, stream>>>(augg, out, bs);
}